// Round 1
// baseline (309.153 us; speedup 1.0000x reference)
//
#include <hip/hip_runtime.h>
#include <math.h>

#define PLANE 4096   // 64*64
#define EPS 1e-5f

typedef float f4 __attribute__((ext_vector_type(4)));

__device__ __forceinline__ float leaky(float x) { return x >= 0.f ? x : 0.01f * x; }

__device__ __forceinline__ float wave_sum(float v) {
    #pragma unroll
    for (int off = 32; off; off >>= 1) v += __shfl_xor(v, off, 64);
    return v;
}

// ---------------- Kernel A: all style-derived small tensors ----------------
// grid = 32: blocks 0..15 -> sd + S for sample n; blocks 16..31 -> d_pred for n.
__global__ __launch_bounds__(256) void style_kernel(
    const float* __restrict__ style,   // [N,512,4,4]
    const float* __restrict__ dw_w,    // [8,512,2,2]
    const float* __restrict__ dw_b,    // [8]
    const float* __restrict__ pk_w,    // [8,512]
    const float* __restrict__ pk_b,    // [8]
    float* __restrict__ sd_out,        // [N,512]
    float* __restrict__ S_out,         // [N]
    float* __restrict__ d_pred)        // [N,72]
{
    const int blk = blockIdx.x;
    const int n = blk & 15;
    const int t = threadIdx.x;
    const int wave = t >> 6, lane = t & 63;
    const float* sb = style + (size_t)n * 8192;

    if (blk < 16) {
        // ---- sd (channel means) + S = sum_o(pk_w[o].sd + pk_b[o]) ----
        __shared__ float s_sd[512];
        __shared__ float red[4];
        #pragma unroll
        for (int q = 0; q < 2; ++q) {
            int c = t + 256 * q;
            const float4* sp = (const float4*)sb + c * 4;
            float4 a = sp[0], b = sp[1], d = sp[2], e = sp[3];
            float s = a.x + a.y + a.z + a.w + b.x + b.y + b.z + b.w
                    + d.x + d.y + d.z + d.w + e.x + e.y + e.z + e.w;
            s *= (1.f / 16.f);
            s_sd[c] = s;
            sd_out[n * 512 + c] = s;
        }
        __syncthreads();
        float part = 0.f;
        #pragma unroll
        for (int o = 0; o < 8; ++o)
            part += pk_w[o * 512 + t] * s_sd[t]
                  + pk_w[o * 512 + t + 256] * s_sd[t + 256];
        part = wave_sum(part);
        if (lane == 0) red[wave] = part;
        __syncthreads();
        if (t == 0) {
            float S = red[0] + red[1] + red[2] + red[3];
            #pragma unroll
            for (int o = 0; o < 8; ++o) S += pk_b[o];
            S_out[n] = S;
        }
    } else {
        // ---- depthwise-kernel predictor: 72 outputs, 4 waves x 18 ----
        const float4* wp = (const float4*)dw_w;
        for (int rr = 0; rr < 18; ++rr) {
            int r = wave * 18 + rr;
            int j = r / 9, pos = r % 9, y = pos / 3, x = pos % 3;
            float acc = 0.f;
            #pragma unroll
            for (int i = 0; i < 8; ++i) {
                int c = lane + 64 * i;
                float4 w = wp[j * 512 + c];
                const float* s = sb + c * 16 + y * 4 + x;
                acc += s[0] * w.x + s[1] * w.y + s[4] * w.z + s[5] * w.w;
            }
            acc = wave_sum(acc);
            if (lane == 0) d_pred[n * 72 + r] = leaky(acc + dw_b[j]);
        }
    }
}

// ---------------- Kernel B: fused bias-GEMV + IN-stats + conv + pointwise + IN ----------------
// one block per (n, group): grid = 16*64 = 1024, block = 256
__global__ __launch_bounds__(256) void fused_kernel(
    const float* __restrict__ content,   // [N,512,64,64]
    const float* __restrict__ d_pred,    // [N,72]
    const float* __restrict__ S_in,      // [N]
    const float* __restrict__ sd,        // [N,512]
    const float* __restrict__ pb_w,      // [512,512]
    const float* __restrict__ pb_b,      // [512]
    float* __restrict__ out)             // [N,512,64,64]
{
    const int b = blockIdx.x;
    const int g = b & 63, n = b >> 6;
    const int t = threadIdx.x;
    const int tx = t & 15, ty = t >> 4;
    const int wave = t >> 6, lane = t & 63;

    __shared__ float s_d[72];
    __shared__ float s_S;
    __shared__ float s_bias[8], s_mean[8], s_rstd[8];
    __shared__ float reds[32], redq[32];

    if (t < 72) s_d[t] = d_pred[n * 72 + t];
    if (t == 80) s_S = S_in[n];

    // ---- bias[o] = pb_w[g*8+o] . sd[n] + pb_b : one half-wave per o ----
    {
        const int o = t >> 5, l = t & 31;
        const float* pw  = pb_w + (size_t)(g * 8 + o) * 512;
        const float* sdn = sd + n * 512;
        float acc = 0.f;
        #pragma unroll
        for (int i = 0; i < 16; ++i) acc += pw[l + 32 * i] * sdn[l + 32 * i];
        #pragma unroll
        for (int off = 16; off; off >>= 1) acc += __shfl_xor(acc, off, 64);
        if (l == 0) s_bias[o] = acc + pb_b[g * 8 + o];
    }

    const float* cbase = content + (size_t)(n * 512 + g * 8) * PLANE;

    // ---- instance-norm stats for the block's 8 channels (single content pass) ----
    #pragma unroll
    for (int j = 0; j < 8; ++j) {
        const float4* p = (const float4*)(cbase + j * PLANE);
        float sm = 0.f, sq = 0.f;
        #pragma unroll
        for (int k = 0; k < 4; ++k) {
            float4 v = p[k * 256 + t];
            sm += v.x + v.y + v.z + v.w;
            sq += v.x * v.x + v.y * v.y + v.z * v.z + v.w * v.w;
        }
        #pragma unroll
        for (int off = 32; off; off >>= 1) {
            sm += __shfl_xor(sm, off, 64);
            sq += __shfl_xor(sq, off, 64);
        }
        if (lane == 0) { reds[j * 4 + wave] = sm; redq[j * 4 + wave] = sq; }
    }
    __syncthreads();
    if (t < 8) {
        float S4 = reds[t * 4] + reds[t * 4 + 1] + reds[t * 4 + 2] + reds[t * 4 + 3];
        float Q4 = redq[t * 4] + redq[t * 4 + 1] + redq[t * 4 + 2] + redq[t * 4 + 3];
        float m = S4 * (1.f / 4096.f);
        float var = (Q4 - 4096.f * m * m) * (1.f / 4095.f);  // ddof=1
        s_mean[t] = m;
        s_rstd[t] = rsqrtf(var + EPS);
    }
    __syncthreads();

    // ---- conv + pointwise-collapse + IN over 4 row-tiles ----
    const float S = s_S;
    #pragma unroll 1
    for (int k = 0; k < 4; ++k) {
        const int h = k * 16 + ty;
        const int x0 = tx * 4;
        float D0 = 0.f, D1 = 0.f, D2 = 0.f, D3 = 0.f;
        float4 xc[8];
        #pragma unroll
        for (int j = 0; j < 8; ++j) {
            const float* cj = cbase + j * PLANE;
            #pragma unroll
            for (int r = 0; r < 3; ++r) {
                int y = h - 1 + r;
                int ry = y < 0 ? 1 : (y > 63 ? 62 : y);   // reflect pad
                float4 v = *(const float4*)(cj + ry * 64 + x0);
                float lv = __shfl_up(v.w, 1, 64);
                float rv = __shfl_down(v.x, 1, 64);
                float xm = (tx == 0)  ? v.y : lv;   // x=-1 reflects to 1
                float xp = (tx == 15) ? v.z : rv;   // x=64 reflects to 62
                const float w0 = s_d[j * 9 + r * 3 + 0];
                const float w1 = s_d[j * 9 + r * 3 + 1];
                const float w2 = s_d[j * 9 + r * 3 + 2];
                D0 += w0 * xm  + w1 * v.x + w2 * v.y;
                D1 += w0 * v.x + w1 * v.y + w2 * v.z;
                D2 += w0 * v.y + w1 * v.z + w2 * v.w;
                D3 += w0 * v.z + w1 * v.w + w2 * xp;
                if (r == 1) xc[j] = v;
            }
        }
        const float P0 = D0 * S, P1 = D1 * S, P2 = D2 * S, P3 = D3 * S;
        float* obase = out + (size_t)(n * 512 + g * 8) * PLANE + h * 64 + x0;
        #pragma unroll
        for (int o = 0; o < 8; ++o) {
            float bb = s_bias[o], m = s_mean[o], rs = s_rstd[o];
            f4 res;
            res.x = (xc[o].x - m) * rs * leaky(P0 + bb);
            res.y = (xc[o].y - m) * rs * leaky(P1 + bb);
            res.z = (xc[o].z - m) * rs * leaky(P2 + bb);
            res.w = (xc[o].w - m) * rs * leaky(P3 + bb);
            // streaming store: out is never re-read; keep L2 for conv halo re-reads
            __builtin_nontemporal_store(res, (f4*)(obase + o * PLANE));
        }
    }
}

extern "C" void kernel_launch(void* const* d_in, const int* in_sizes, int n_in,
                              void* d_out, int out_size, void* d_ws, size_t ws_size,
                              hipStream_t stream) {
    const float* style   = (const float*)d_in[0];
    const float* content = (const float*)d_in[1];
    const float* dw_w    = (const float*)d_in[2];
    const float* dw_b    = (const float*)d_in[3];
    const float* pk_w    = (const float*)d_in[4];
    const float* pk_b    = (const float*)d_in[5];
    const float* pb_w    = (const float*)d_in[6];
    const float* pb_b    = (const float*)d_in[7];
    float* out = (float*)d_out;
    float* ws  = (float*)d_ws;

    const int N = 16;
    float* sd_ws  = ws;                   // N*512
    float* d_pred = sd_ws + N * 512;      // N*72
    float* S_ws   = d_pred + N * 72;      // N

    style_kernel<<<32, 256, 0, stream>>>(style, dw_w, dw_b, pk_w, pk_b,
                                         sd_ws, S_ws, d_pred);
    fused_kernel<<<N * 64, 256, 0, stream>>>(content, d_pred, S_ws, sd_ws,
                                             pb_w, pb_b, out);
}

// Round 2
// 292.331 us; speedup vs baseline: 1.0575x; 1.0575x over previous
//
#include <hip/hip_runtime.h>
#include <math.h>

#define PLANE 4096   // 64*64
#define EPS 1e-5f

typedef float f4 __attribute__((ext_vector_type(4)));

__device__ __forceinline__ float leaky(float x) { return x >= 0.f ? x : 0.01f * x; }

__device__ __forceinline__ float wave_sum(float v) {
    #pragma unroll
    for (int off = 32; off; off >>= 1) v += __shfl_xor(v, off, 64);
    return v;
}

// ---------------- Kernel 1: prep (stats + all style-derived tensors) ----------------
// blocks [0,8192): per-(n,c) instance-norm stats
// blocks [8192,8208): sd channel-means + S scalar, one block per n
// blocks [8208,8224): depthwise-kernel predictor conv, one block per n
__global__ __launch_bounds__(256) void prep_kernel(
    const float* __restrict__ style,     // [N,512,4,4]
    const float* __restrict__ content,   // [N,512,64,64]
    const float* __restrict__ dw_w,      // [8,512,2,2]
    const float* __restrict__ dw_b,      // [8]
    const float* __restrict__ pk_w,      // [8,512]
    const float* __restrict__ pk_b,      // [8]
    float* __restrict__ sd_out,          // [N,512]
    float* __restrict__ S_out,           // [N]
    float* __restrict__ d_pred,          // [N,72]
    float* __restrict__ mean_out,        // [N*512]
    float* __restrict__ rstd_out)        // [N*512]
{
    const int blk = blockIdx.x;
    const int t = threadIdx.x;
    const int wave = t >> 6, lane = t & 63;

    __shared__ float ls[4], lq[4];
    __shared__ float s_sd[512];
    __shared__ float red[4];

    if (blk < 8192) {
        // ---- instance-norm stats for plane nc = blk ----
        const float4* base = (const float4*)(content + (size_t)blk * PLANE);
        float s = 0.f, q = 0.f;
        #pragma unroll
        for (int k = 0; k < 4; ++k) {
            float4 v = base[k * 256 + t];
            s += v.x + v.y + v.z + v.w;
            q += v.x * v.x + v.y * v.y + v.z * v.z + v.w * v.w;
        }
        #pragma unroll
        for (int off = 32; off; off >>= 1) {
            s += __shfl_xor(s, off, 64);
            q += __shfl_xor(q, off, 64);
        }
        if (lane == 0) { ls[wave] = s; lq[wave] = q; }
        __syncthreads();
        if (t == 0) {
            float S = ls[0] + ls[1] + ls[2] + ls[3];
            float Q = lq[0] + lq[1] + lq[2] + lq[3];
            float m = S * (1.f / 4096.f);
            float var = (Q - 4096.f * m * m) * (1.f / 4095.f);  // ddof=1
            mean_out[blk] = m;
            rstd_out[blk] = rsqrtf(var + EPS);
        }
    } else if (blk < 8208) {
        // ---- sd (channel means) + S = sum_o(pk_w[o].sd + pk_b[o]) ----
        const int n = blk - 8192;
        const float* sb = style + (size_t)n * 8192;
        #pragma unroll
        for (int qd = 0; qd < 2; ++qd) {
            int c = t + 256 * qd;
            const float4* sp = (const float4*)sb + c * 4;
            float4 a = sp[0], b = sp[1], d = sp[2], e = sp[3];
            float s = a.x + a.y + a.z + a.w + b.x + b.y + b.z + b.w
                    + d.x + d.y + d.z + d.w + e.x + e.y + e.z + e.w;
            s *= (1.f / 16.f);
            s_sd[c] = s;
            sd_out[n * 512 + c] = s;
        }
        __syncthreads();
        float part = 0.f;
        #pragma unroll
        for (int o = 0; o < 8; ++o)
            part += pk_w[o * 512 + t] * s_sd[t]
                  + pk_w[o * 512 + t + 256] * s_sd[t + 256];
        part = wave_sum(part);
        if (lane == 0) red[wave] = part;
        __syncthreads();
        if (t == 0) {
            float S = red[0] + red[1] + red[2] + red[3];
            #pragma unroll
            for (int o = 0; o < 8; ++o) S += pk_b[o];
            S_out[n] = S;
        }
    } else {
        // ---- depthwise-kernel predictor: 72 outputs, 4 waves x 18 ----
        const int n = blk - 8208;
        const float* sb = style + (size_t)n * 8192;
        const float4* wp = (const float4*)dw_w;
        for (int rr = 0; rr < 18; ++rr) {
            int r = wave * 18 + rr;
            int j = r / 9, pos = r % 9, y = pos / 3, x = pos % 3;
            float acc = 0.f;
            #pragma unroll
            for (int i = 0; i < 8; ++i) {
                int c = lane + 64 * i;
                float4 w = wp[j * 512 + c];
                const float* s = sb + c * 16 + y * 4 + x;
                acc += s[0] * w.x + s[1] * w.y + s[4] * w.z + s[5] * w.w;
            }
            acc = wave_sum(acc);
            if (lane == 0) d_pred[n * 72 + r] = leaky(acc + dw_b[j]);
        }
    }
}

// ---------------- Kernel 2: conv + pointwise-collapse + IN (+ bias GEMV) ----------------
// one block per (n, group, row-tile): grid = 16*64*4 = 4096, block = 256
__global__ __launch_bounds__(256, 3) void main_kernel(
    const float* __restrict__ content,   // [N,512,64,64]
    const float* __restrict__ d_pred,    // [N,72]
    const float* __restrict__ S_in,      // [N]
    const float* __restrict__ sd,        // [N,512]
    const float* __restrict__ pb_w,      // [512,512]
    const float* __restrict__ pb_b,      // [512]
    const float* __restrict__ mean_in,   // [N*512]
    const float* __restrict__ rstd_in,   // [N*512]
    float* __restrict__ out)             // [N,512,64,64]
{
    const int b    = blockIdx.x;
    const int tile = b & 3;
    const int g    = (b >> 2) & 63;
    const int n    = b >> 8;
    const int t  = threadIdx.x;
    const int tx = t & 15, ty = t >> 4;
    const int h  = tile * 16 + ty;
    const int x0 = tx * 4;

    __shared__ float s_d[72];
    __shared__ float s_S;
    __shared__ float s_bias[8], s_mean[8], s_rstd[8];

    if (t < 72) s_d[t] = d_pred[n * 72 + t];
    if (t == 80) s_S = S_in[n];
    if (t >= 96 && t < 104) {
        int o = t - 96;
        int c = n * 512 + g * 8 + o;
        s_mean[o] = mean_in[c];
        s_rstd[o] = rstd_in[c];
    }
    // ---- bias[o] = pb_w[g*8+o] . sd[n] + pb_b : one half-wave per o ----
    {
        const int o = t >> 5, l = t & 31;
        const float* pw  = pb_w + (size_t)(g * 8 + o) * 512;
        const float* sdn = sd + n * 512;
        float acc = 0.f;
        #pragma unroll
        for (int i = 0; i < 16; ++i) acc += pw[l + 32 * i] * sdn[l + 32 * i];
        #pragma unroll
        for (int off = 16; off; off >>= 1) acc += __shfl_xor(acc, off, 64);
        if (l == 0) s_bias[o] = acc + pb_b[g * 8 + o];
    }
    __syncthreads();

    const float* cbase = content + (size_t)(n * 512 + g * 8) * PLANE;
    float D0 = 0.f, D1 = 0.f, D2 = 0.f, D3 = 0.f;

    #pragma unroll
    for (int j = 0; j < 8; ++j) {
        const float* cj = cbase + j * PLANE;
        #pragma unroll
        for (int r = 0; r < 3; ++r) {
            int y = h - 1 + r;
            int ry = y < 0 ? 1 : (y > 63 ? 62 : y);   // reflect pad
            float4 v = *(const float4*)(cj + ry * 64 + x0);
            float lv = __shfl_up(v.w, 1, 64);
            float rv = __shfl_down(v.x, 1, 64);
            float xm = (tx == 0)  ? v.y : lv;   // x=-1 reflects to 1
            float xp = (tx == 15) ? v.z : rv;   // x=64 reflects to 62
            const float w0 = s_d[j * 9 + r * 3 + 0];
            const float w1 = s_d[j * 9 + r * 3 + 1];
            const float w2 = s_d[j * 9 + r * 3 + 2];
            D0 += w0 * xm  + w1 * v.x + w2 * v.y;
            D1 += w0 * v.x + w1 * v.y + w2 * v.z;
            D2 += w0 * v.y + w1 * v.z + w2 * v.w;
            D3 += w0 * v.z + w1 * v.w + w2 * xp;
        }
    }

    const float S = s_S;
    const float P0 = D0 * S, P1 = D1 * S, P2 = D2 * S, P3 = D3 * S;
    float* obase = out + (size_t)(n * 512 + g * 8) * PLANE + h * 64 + x0;
    #pragma unroll
    for (int o = 0; o < 8; ++o) {
        // re-load center values (L1/L2-hot: just read in the conv loop)
        float4 v = *(const float4*)(cbase + o * PLANE + h * 64 + x0);
        float bb = s_bias[o], m = s_mean[o], rs = s_rstd[o];
        f4 res;
        res.x = (v.x - m) * rs * leaky(P0 + bb);
        res.y = (v.y - m) * rs * leaky(P1 + bb);
        res.z = (v.z - m) * rs * leaky(P2 + bb);
        res.w = (v.w - m) * rs * leaky(P3 + bb);
        // streaming store: out is never re-read; keep L2 for content re-reads
        __builtin_nontemporal_store(res, (f4*)(obase + o * PLANE));
    }
}

extern "C" void kernel_launch(void* const* d_in, const int* in_sizes, int n_in,
                              void* d_out, int out_size, void* d_ws, size_t ws_size,
                              hipStream_t stream) {
    const float* style   = (const float*)d_in[0];
    const float* content = (const float*)d_in[1];
    const float* dw_w    = (const float*)d_in[2];
    const float* dw_b    = (const float*)d_in[3];
    const float* pk_w    = (const float*)d_in[4];
    const float* pk_b    = (const float*)d_in[5];
    const float* pb_w    = (const float*)d_in[6];
    const float* pb_b    = (const float*)d_in[7];
    float* out = (float*)d_out;
    float* ws  = (float*)d_ws;

    const int N = 16;
    float* sd_ws   = ws;                  // N*512
    float* d_pred  = sd_ws + N * 512;     // N*72
    float* S_ws    = d_pred + N * 72;     // N
    float* mean_ws = S_ws + N;            // N*512
    float* rstd_ws = mean_ws + N * 512;   // N*512

    prep_kernel<<<8224, 256, 0, stream>>>(style, content, dw_w, dw_b, pk_w, pk_b,
                                          sd_ws, S_ws, d_pred, mean_ws, rstd_ws);
    main_kernel<<<N * 64 * 4, 256, 0, stream>>>(content, d_pred, S_ws, sd_ws,
                                                pb_w, pb_b, mean_ws, rstd_ws, out);
}